// Round 1
// baseline (51.030 us; speedup 1.0000x reference)
//
#include <hip/hip_runtime.h>

#define FD 768
#define HD 256
#define NF 512

// ---------------------------------------------------------------------------
// Kernel 1: C[r][c] = sum_d E[r][d] * Wcat[d][c]  (+ b1[c] for c < 256)
//   Wcat = [W1_top | W1_bot], W1 is [1536][256] row-major.
//   C is [512][512]: left half = A (e@W1_top + b1), right half = B (e@W1_bot).
// Tiled 32x32, 256 threads, 2x2 micro-tile, LDS stride 33 (conflict-free).
// ---------------------------------------------------------------------------
__global__ __launch_bounds__(256) void gemm_kernel(const float* __restrict__ E,
                                                   const float* __restrict__ W1,
                                                   const float* __restrict__ b1,
                                                   float* __restrict__ C) {
    __shared__ float Es[32 * 33];
    __shared__ float Ws[32 * 33];
    const int bx = blockIdx.x;        // col tile 0..15 (8 for A half, 8 for B half)
    const int by = blockIdx.y;        // row tile 0..15
    const int tid = threadIdx.x;
    const int tx = tid & 15, ty = tid >> 4;
    const int r0   = by * 32;
    const int halfB = (bx >= 8);
    const int c0g  = bx * 32;         // column in C
    const int c0w  = (bx & 7) * 32;   // column within the W1 half
    const int dofs = halfB ? FD : 0;  // row offset into W1 (top vs bottom half)

    float acc00 = 0.f, acc01 = 0.f, acc10 = 0.f, acc11 = 0.f;

    for (int d0 = 0; d0 < FD; d0 += 32) {
        #pragma unroll
        for (int t = 0; t < 4; ++t) {
            int e = tid + t * 256;            // 1024 elements, 4 per thread
            int row = e >> 5, col = e & 31;   // coalesced: consecutive tid -> consecutive col
            Es[row * 33 + col] = E[(r0 + row) * FD + d0 + col];
            Ws[row * 33 + col] = W1[(dofs + d0 + row) * HD + c0w + col];
        }
        __syncthreads();
        #pragma unroll
        for (int kk = 0; kk < 32; ++kk) {
            float a0 = Es[ty * 33 + kk];
            float a1 = Es[(ty + 16) * 33 + kk];
            float w0 = Ws[kk * 33 + tx];
            float w1 = Ws[kk * 33 + tx + 16];
            acc00 = fmaf(a0, w0, acc00);
            acc01 = fmaf(a0, w1, acc01);
            acc10 = fmaf(a1, w0, acc10);
            acc11 = fmaf(a1, w1, acc11);
        }
        __syncthreads();
    }

    float bb0 = 0.f, bb1 = 0.f;
    if (!halfB) { bb0 = b1[c0w + tx]; bb1 = b1[c0w + tx + 16]; }
    C[(r0 + ty) * 512 + c0g + tx]           = acc00 + bb0;
    C[(r0 + ty) * 512 + c0g + tx + 16]      = acc01 + bb1;
    C[(r0 + ty + 16) * 512 + c0g + tx]      = acc10 + bb0;
    C[(r0 + ty + 16) * 512 + c0g + tx + 16] = acc11 + bb1;
}

// ---------------------------------------------------------------------------
// Kernel 2: for each pair (i, j>i): score = relu(A[i] + B[j]) . W2 + b2
//   One block = 16x16 pair tile; 256 threads, one pair per thread.
//   A-rows / B-rows staged in LDS with odd stride 257 (conflict-free reads:
//   addr = row*257 + k -> bank (row + k) % 32, distinct across lanes).
//   Outputs: out[0..P) = i (float), out[P..2P) = j, out[2P..3P) = score.
// ---------------------------------------------------------------------------
__global__ __launch_bounds__(256) void pair_kernel(const float* __restrict__ C,
                                                   const float* __restrict__ W2,
                                                   const float* __restrict__ b2,
                                                   float* __restrict__ out) {
    __shared__ float As[16 * 257];
    __shared__ float Bs[16 * 257];
    __shared__ float w2s[HD];

    // decode upper-triangular tile index (bi <= bj), nt = 32 tiles per side
    const int nt = NF / 16;           // 32
    int rem = blockIdx.x;
    int bi = 0;
    while (rem >= nt - bi) { rem -= nt - bi; ++bi; }
    const int bj = bi + rem;
    const int i0 = bi * 16, j0 = bj * 16;

    const int tid = threadIdx.x;
    w2s[tid] = W2[tid];               // HD == blockDim == 256

    #pragma unroll
    for (int t = 0; t < 16; ++t) {    // 16 rows x 256 cols per array, 16 loads/thread
        int e = tid + t * 256;
        int row = e >> 8, k = e & 255;
        As[row * 257 + k] = C[(i0 + row) * 512 + k];          // A half
        Bs[row * 257 + k] = C[(j0 + row) * 512 + HD + k];     // B half
    }
    __syncthreads();

    const int tx = tid & 15, ty = tid >> 4;
    const int i = i0 + ty, j = j0 + tx;

    const float* ap = &As[ty * 257];
    const float* bp = &Bs[tx * 257];
    float acc = 0.f;
    #pragma unroll 8
    for (int k = 0; k < HD; ++k) {
        float h = ap[k] + bp[k];
        h = fmaxf(h, 0.f);
        acc = fmaf(h, w2s[k], acc);
    }

    if (j > i) {
        const int n = NF;
        const int P = n * (n - 1) / 2;                 // 130816
        const int p = i * (2 * n - i - 1) / 2 + (j - i - 1);
        out[p]         = (float)i;
        out[P + p]     = (float)j;
        out[2 * P + p] = acc + b2[0];
    }
}

extern "C" void kernel_launch(void* const* d_in, const int* in_sizes, int n_in,
                              void* d_out, int out_size, void* d_ws, size_t ws_size,
                              hipStream_t stream) {
    const float* E  = (const float*)d_in[0];   // [512][768]
    const float* W1 = (const float*)d_in[1];   // [1536][256]
    const float* b1 = (const float*)d_in[2];   // [256]
    const float* W2 = (const float*)d_in[3];   // [256][1]
    const float* b2 = (const float*)d_in[4];   // [1]
    float* out = (float*)d_out;                // 3*P floats
    float* C   = (float*)d_ws;                 // [512][512] scratch (1 MiB)

    gemm_kernel<<<dim3(16, 16), 256, 0, stream>>>(E, W1, b1, C);
    pair_kernel<<<NF / 16 * (NF / 16 + 1) / 2, 256, 0, stream>>>(C, W2, b2, out);
}

// Round 2
// 45.814 us; speedup vs baseline: 1.1139x; 1.1139x over previous
//
#include <hip/hip_runtime.h>

#define FD 768
#define HD 256
#define NF 512
#define NC 512                      // C cols = 2*HD
#define PAIRS (NF * (NF - 1) / 2)   // 130816

// ---------------------------------------------------------------------------
// Split-K GEMM: part[z][r][c] = sum_{d in K-slice z} E[r][d] * Wcat[d][c]
//   Wcat[d][c] = W1[d][c] (c<256) | W1[FD+d][c-256] (c>=256). Bias NOT added
//   here (added once during pair staging).
// Grid (16 col-tiles, 16 row-tiles, nsplit). 256 thr, 32x32 tile,
// microtile = 1 row x 4 contiguous cols (float4 acc).
// K-chunk 64. LDS: Es 32x68 (pad 4), Ws 64x36 (pad 4) — conflict-free.
// ---------------------------------------------------------------------------
__global__ __launch_bounds__(256) void gemm_split_kernel(
    const float* __restrict__ E, const float* __restrict__ W1,
    float* __restrict__ part, int ksz)
{
    __shared__ float4 Es4[32 * 17];   // 32 rows x 68 floats
    __shared__ float4 Ws4[64 * 9];    // 64 k-rows x 36 floats
    float* Es = (float*)Es4;

    const int tid = threadIdx.x;
    const int bx = blockIdx.x, by = blockIdx.y, z = blockIdx.z;
    const int r0   = by * 32;
    const int c0g  = bx * 32;              // column in C
    const int c0w  = (bx & 7) * 32;        // column within the W1 half
    const int dofs = (bx >= 8) ? FD : 0;   // top vs bottom half of W1

    const int r = tid >> 3;   // 0..31 output row
    const int c = tid & 7;    // cols 4c..4c+3

    float4 acc = {0.f, 0.f, 0.f, 0.f};

    const int d_end = (z + 1) * ksz;
    for (int d0 = z * ksz; d0 < d_end; d0 += 64) {
        #pragma unroll
        for (int s = 0; s < 2; ++s) {
            int e = tid + s * 256;
            int er = e >> 4, ec4 = e & 15;                 // E: 32 rows x 16 f4
            Es4[er * 17 + ec4] = *(const float4*)&E[(r0 + er) * FD + d0 + 4 * ec4];
            int wr = e >> 3, wc4 = e & 7;                  // W: 64 rows x 8 f4
            Ws4[wr * 9 + wc4] = *(const float4*)&W1[(dofs + d0 + wr) * HD + c0w + 4 * wc4];
        }
        __syncthreads();
        #pragma unroll
        for (int kk = 0; kk < 64; ++kk) {
            float  a = Es[r * 68 + kk];        // broadcast (8 addrs/wave)
            float4 w = Ws4[kk * 9 + c];        // b128, 8 distinct bank-quads
            acc.x = fmaf(a, w.x, acc.x);
            acc.y = fmaf(a, w.y, acc.y);
            acc.z = fmaf(a, w.z, acc.z);
            acc.w = fmaf(a, w.w, acc.w);
        }
        __syncthreads();
    }
    *(float4*)&part[(size_t)z * NF * NC + (r0 + r) * NC + c0g + 4 * c] = acc;
}

// ---------------------------------------------------------------------------
// Pair kernel: per 16x16 (i,j>i) tile, stage A rows (+sum partials +b1) and
// B rows (+sum partials) in LDS (row stride 65 float4 -> b128 reads max
// 2-way = free), then score = relu(A[i]+B[j]) . W2 + b2, one pair/thread.
// ---------------------------------------------------------------------------
__global__ __launch_bounds__(256) void pair_kernel(
    const float* __restrict__ Csrc, const float* __restrict__ b1,
    const float* __restrict__ W2, const float* __restrict__ b2,
    float* __restrict__ out, int nsplit)
{
    __shared__ float4 As4[16 * 65];
    __shared__ float4 Bs4[16 * 65];
    __shared__ float4 w2s4[HD / 4];

    const int nt = NF / 16;   // 32 tiles per side
    int rem = blockIdx.x;
    int bi = 0;
    while (rem >= nt - bi) { rem -= nt - bi; ++bi; }
    const int bj = bi + rem;
    const int i0 = bi * 16, j0 = bj * 16;

    const int tid = threadIdx.x;
    ((float*)w2s4)[tid] = W2[tid];

    const float4* C4  = (const float4*)Csrc;   // partial z at z*65536 f4
    const float4* b14 = (const float4*)b1;

    #pragma unroll
    for (int s = 0; s < 4; ++s) {
        int e = tid + s * 256;
        int row = e >> 6, c4 = e & 63;         // 16 rows x 64 f4 per array
        float4 va = {0.f, 0.f, 0.f, 0.f};
        float4 vb = {0.f, 0.f, 0.f, 0.f};
        for (int zz = 0; zz < nsplit; ++zz) {
            float4 pa = C4[zz * 65536 + (i0 + row) * 128 + c4];       // A half
            float4 pb = C4[zz * 65536 + (j0 + row) * 128 + 64 + c4];  // B half
            va.x += pa.x; va.y += pa.y; va.z += pa.z; va.w += pa.w;
            vb.x += pb.x; vb.y += pb.y; vb.z += pb.z; vb.w += pb.w;
        }
        float4 bb = b14[c4];
        va.x += bb.x; va.y += bb.y; va.z += bb.z; va.w += bb.w;
        As4[row * 65 + c4] = va;
        Bs4[row * 65 + c4] = vb;
    }
    __syncthreads();

    const int tx = tid & 15, ty = tid >> 4;
    const int i = i0 + ty, j = j0 + tx;

    float acc = 0.f;
    #pragma unroll
    for (int k4 = 0; k4 < HD / 4; ++k4) {
        float4 a = As4[ty * 65 + k4];   // broadcast (4 addrs/wave)
        float4 b = Bs4[tx * 65 + k4];   // 16 addrs, 2-way = free
        float4 w = w2s4[k4];            // uniform
        acc = fmaf(fmaxf(a.x + b.x, 0.f), w.x, acc);
        acc = fmaf(fmaxf(a.y + b.y, 0.f), w.y, acc);
        acc = fmaf(fmaxf(a.z + b.z, 0.f), w.z, acc);
        acc = fmaf(fmaxf(a.w + b.w, 0.f), w.w, acc);
    }

    if (j > i) {
        const int p = i * (2 * NF - i - 1) / 2 + (j - i - 1);
        out[p]             = (float)i;
        out[PAIRS + p]     = (float)j;
        out[2 * PAIRS + p] = acc + b2[0];
    }
}

extern "C" void kernel_launch(void* const* d_in, const int* in_sizes, int n_in,
                              void* d_out, int out_size, void* d_ws, size_t ws_size,
                              hipStream_t stream) {
    const float* E  = (const float*)d_in[0];   // [512][768]
    const float* W1 = (const float*)d_in[1];   // [1536][256]
    const float* b1 = (const float*)d_in[2];   // [256]
    const float* W2 = (const float*)d_in[3];   // [256][1]
    const float* b2 = (const float*)d_in[4];   // [1]
    float* out  = (float*)d_out;
    float* part = (float*)d_ws;

    // nsplit partials of 1 MiB each; 768 divisible by 1,2,3,4.
    size_t avail = ws_size / ((size_t)NF * NC * sizeof(float));
    int nsplit = (avail >= 4) ? 4 : (avail >= 3) ? 3 : (avail >= 2) ? 2 : 1;
    int ksz = FD / nsplit;

    gemm_split_kernel<<<dim3(16, 16, nsplit), 256, 0, stream>>>(E, W1, part, ksz);
    pair_kernel<<<NF / 16 * (NF / 16 + 1) / 2, 256, 0, stream>>>(part, b1, W2, b2, out, nsplit);
}

// Round 3
// 29.815 us; speedup vs baseline: 1.7115x; 1.5366x over previous
//
#include <hip/hip_runtime.h>

#define FD 768
#define HD 256
#define NF 512
#define NC 512
#define PAIRS (NF * (NF - 1) / 2)   // 130816
#define NS 8                        // split-k factor
#define KSLICE (FD / NS)            // 96
#define KC 32                       // k-chunk per staging round

// ---------------------------------------------------------------------------
// Kernel 1: split-K GEMM, 64x64 tile, 4x4 register microtile.
//   part[z][r][c] = sum_{d in slice z} E[r][d] * Wcat[d][c]
// LDS: Es[64][36] row-major with k-quad XOR swizzle key (row>>2)&7
//      (A-reads: 4-addr broadcast b128, distinct bank-quads -> conflict-free)
//      Ws[32][68] row-major (W-reads: 16 addrs, quad=(4kq+k+tx)%8 -> free)
// ---------------------------------------------------------------------------
__global__ __launch_bounds__(256) void gemm_split_kernel(
    const float* __restrict__ E, const float* __restrict__ W1,
    float* __restrict__ part)
{
    __shared__ float Es[64 * 36];
    __shared__ float Ws[32 * 68];

    const int tid = threadIdx.x;
    const int bx = blockIdx.x, by = blockIdx.y, bz = blockIdx.z;
    const int r0   = by * 64;
    const int c0g  = bx * 64;
    const int c0w  = c0g & 255;
    const int dofs = (c0g >= 256) ? FD : 0;
    const int tx = tid & 15, ty = tid >> 4;   // cols 4tx.., rows 4ty..
    const int akey = ty & 7;

    float4 acc0 = {0,0,0,0}, acc1 = {0,0,0,0}, acc2 = {0,0,0,0}, acc3 = {0,0,0,0};

    for (int it = 0; it < KSLICE / KC; ++it) {
        const int dbase = bz * KSLICE + it * KC;
        #pragma unroll
        for (int s = 0; s < 2; ++s) {
            int e = tid + 256 * s;
            int er = e >> 3, ec = e & 7;               // E-tile: 64 rows x 8 f4
            float4 v = *(const float4*)&E[(r0 + er) * FD + dbase + 4 * ec];
            *(float4*)&Es[er * 36 + 4 * (ec ^ ((er >> 2) & 7))] = v;
            int wr = e >> 4, wc = e & 15;              // W-tile: 32 rows x 16 f4
            float4 w = *(const float4*)&W1[(dofs + dbase + wr) * HD + c0w + 4 * wc];
            *(float4*)&Ws[wr * 68 + 4 * wc] = w;
        }
        __syncthreads();

        #pragma unroll
        for (int kq = 0; kq < KC / 4; ++kq) {
            const int ko = 4 * (kq ^ akey);
            float4 a0 = *(const float4*)&Es[(4 * ty + 0) * 36 + ko];
            float4 a1 = *(const float4*)&Es[(4 * ty + 1) * 36 + ko];
            float4 a2 = *(const float4*)&Es[(4 * ty + 2) * 36 + ko];
            float4 a3 = *(const float4*)&Es[(4 * ty + 3) * 36 + ko];
            float4 w0 = *(const float4*)&Ws[(4 * kq + 0) * 68 + 4 * tx];
            float4 w1 = *(const float4*)&Ws[(4 * kq + 1) * 68 + 4 * tx];
            float4 w2 = *(const float4*)&Ws[(4 * kq + 2) * 68 + 4 * tx];
            float4 w3 = *(const float4*)&Ws[(4 * kq + 3) * 68 + 4 * tx];
            #define FMA4(ACC, S, W) \
                ACC.x = fmaf(S, W.x, ACC.x); ACC.y = fmaf(S, W.y, ACC.y); \
                ACC.z = fmaf(S, W.z, ACC.z); ACC.w = fmaf(S, W.w, ACC.w);
            FMA4(acc0, a0.x, w0) FMA4(acc0, a0.y, w1) FMA4(acc0, a0.z, w2) FMA4(acc0, a0.w, w3)
            FMA4(acc1, a1.x, w0) FMA4(acc1, a1.y, w1) FMA4(acc1, a1.z, w2) FMA4(acc1, a1.w, w3)
            FMA4(acc2, a2.x, w0) FMA4(acc2, a2.y, w1) FMA4(acc2, a2.z, w2) FMA4(acc2, a2.w, w3)
            FMA4(acc3, a3.x, w0) FMA4(acc3, a3.y, w1) FMA4(acc3, a3.z, w2) FMA4(acc3, a3.w, w3)
            #undef FMA4
        }
        __syncthreads();
    }

    float* dst = &part[(size_t)bz * NF * NC + (size_t)(r0 + 4 * ty) * NC + c0g + 4 * tx];
    *(float4*)&dst[0 * NC] = acc0;
    *(float4*)&dst[1 * NC] = acc1;
    *(float4*)&dst[2 * NC] = acc2;
    *(float4*)&dst[3 * NC] = acc3;
}

// ---------------------------------------------------------------------------
// Kernel 2: C = sum_z part[z] (+ b1 on the left half). 512 blocks x 128 thr.
// ---------------------------------------------------------------------------
__global__ __launch_bounds__(128) void reduce_kernel(
    const float* __restrict__ part, const float* __restrict__ b1,
    float* __restrict__ C)
{
    const int idx = blockIdx.x * 128 + threadIdx.x;   // 0..65535 (f4 index)
    const float4* p4 = (const float4*)part;
    float4 s = p4[idx];
    #pragma unroll
    for (int z = 1; z < NS; ++z) {
        float4 v = p4[z * (NF * NC / 4) + idx];
        s.x += v.x; s.y += v.y; s.z += v.z; s.w += v.w;
    }
    const int c4 = idx & 127;
    if (c4 < 64) {
        float4 b = ((const float4*)b1)[c4];
        s.x += b.x; s.y += b.y; s.z += b.z; s.w += b.w;
    }
    ((float4*)C)[idx] = s;
}

// ---------------------------------------------------------------------------
// Kernel 3: pair scores. 32x32 pair tile per block (bi<=bj triangular, 136
// blocks), 2x2 microtile (4 pairs/thread). A/B rows in LDS as float4[32][64]
// with k4 XOR swizzle key (row>>1)&7: a-reads 4-addr broadcast, b-reads 8
// distinct quads x2 -> conflict-free.
// ---------------------------------------------------------------------------
__global__ __launch_bounds__(256) void pair_kernel(
    const float* __restrict__ C, const float* __restrict__ W2,
    const float* __restrict__ b2, float* __restrict__ out)
{
    __shared__ float4 As[32 * 64];
    __shared__ float4 Bs[32 * 64];
    __shared__ float4 w2s[HD / 4];

    int rem = blockIdx.x, bi = 0;
    while (rem >= 16 - bi) { rem -= 16 - bi; ++bi; }
    const int bj = bi + rem;
    const int i0 = bi * 32, j0 = bj * 32;

    const int tid = threadIdx.x;
    ((float*)w2s)[tid] = W2[tid];

    const float4* C4 = (const float4*)C;   // row pitch 128 f4
    #pragma unroll
    for (int s = 0; s < 8; ++s) {
        int e = tid + 256 * s;
        int row = e >> 6, c4 = e & 63;
        int sc4 = c4 ^ ((row >> 1) & 7);
        As[row * 64 + sc4] = C4[(i0 + row) * 128 + c4];        // A half
        Bs[row * 64 + sc4] = C4[(j0 + row) * 128 + 64 + c4];   // B half
    }
    __syncthreads();

    const int tx = tid & 15, ty = tid >> 4;
    const int ka = ty & 7, kb = tx & 7;
    float acc00 = 0.f, acc01 = 0.f, acc10 = 0.f, acc11 = 0.f;

    #pragma unroll 8
    for (int k4 = 0; k4 < HD / 4; ++k4) {
        float4 a0 = As[(2 * ty + 0) * 64 + (k4 ^ ka)];
        float4 a1 = As[(2 * ty + 1) * 64 + (k4 ^ ka)];
        float4 b0 = Bs[(2 * tx + 0) * 64 + (k4 ^ kb)];
        float4 b1v = Bs[(2 * tx + 1) * 64 + (k4 ^ kb)];
        float4 w = w2s[k4];
        #define PACC(ACC, A, B) \
            ACC = fmaf(fmaxf(A.x + B.x, 0.f), w.x, ACC); \
            ACC = fmaf(fmaxf(A.y + B.y, 0.f), w.y, ACC); \
            ACC = fmaf(fmaxf(A.z + B.z, 0.f), w.z, ACC); \
            ACC = fmaf(fmaxf(A.w + B.w, 0.f), w.w, ACC);
        PACC(acc00, a0, b0) PACC(acc01, a0, b1v)
        PACC(acc10, a1, b0) PACC(acc11, a1, b1v)
        #undef PACC
    }

    const float bias2 = b2[0];
    #pragma unroll
    for (int u = 0; u < 4; ++u) {
        int i = i0 + 2 * ty + (u >> 1);
        int j = j0 + 2 * tx + (u & 1);
        float v = (u == 0) ? acc00 : (u == 1) ? acc01 : (u == 2) ? acc10 : acc11;
        if (j > i) {
            int p = i * (2 * NF - i - 1) / 2 + (j - i - 1);
            out[p]             = (float)i;
            out[PAIRS + p]     = (float)j;
            out[2 * PAIRS + p] = v + bias2;
        }
    }
}

extern "C" void kernel_launch(void* const* d_in, const int* in_sizes, int n_in,
                              void* d_out, int out_size, void* d_ws, size_t ws_size,
                              hipStream_t stream) {
    const float* E  = (const float*)d_in[0];
    const float* W1 = (const float*)d_in[1];
    const float* b1 = (const float*)d_in[2];
    const float* W2 = (const float*)d_in[3];
    const float* b2 = (const float*)d_in[4];
    float* out  = (float*)d_out;
    float* part = (float*)d_ws;                            // NS MiB of partials
    float* C    = (float*)d_ws + (size_t)NS * NF * NC;     // 1 MiB reduced C

    gemm_split_kernel<<<dim3(8, 8, NS), 256, 0, stream>>>(E, W1, part);
    reduce_kernel<<<NF * NC / 4 / 128, 128, 0, stream>>>(part, b1, C);
    pair_kernel<<<136, 256, 0, stream>>>(C, W2, b2, out);
}